// Round 5
// baseline (2319.367 us; speedup 1.0000x reference)
//
#include <hip/hip_runtime.h>

typedef float F2 __attribute__((ext_vector_type(2)));

#define NB 4
#define NC 17
#define T0 75000
#define NH 32
#define NK 8

// pack k into low 3 mantissa bits so fmax/fmin trees carry the arg-index
__device__ __forceinline__ float packK(float z, int k) {
    unsigned u = (__float_as_uint(z) & 0xFFFFFFF8u) | (unsigned)k;
    return __uint_as_float(u);
}
__device__ __forceinline__ float max8(const float* p) {
    return fmaxf(fmaxf(fmaxf(p[0], p[1]), fmaxf(p[2], p[3])),
                 fmaxf(fmaxf(p[4], p[5]), fmaxf(p[6], p[7])));
}
__device__ __forceinline__ float min8(const float* p) {
    return fminf(fminf(fminf(p[0], p[1]), fminf(p[2], p[3])),
                 fminf(fminf(p[4], p[5]), fminf(p[6], p[7])));
}

// k-paired weight load: w2[j*4+kp] = {W[2kp][j], W[2kp+1][j]} (block-uniform -> SGPRs)
__device__ __forceinline__ void load_w2(const float* __restrict__ wp, F2* w2) {
#pragma unroll
    for (int j = 0; j < 9; ++j)
#pragma unroll
        for (int kp = 0; kp < 4; ++kp)
            w2[j * 4 + kp] = (F2){wp[(2 * kp) * 9 + j], wp[(2 * kp + 1) * 9 + j]};
}

// reduce maxb[8][256] and minb[8][256] -> 16 atomics
__device__ __forceinline__ void block_reduce_out(const float* maxb, const float* minb,
                                                 int tid, int ga, int b, int h,
                                                 float* out) {
    __syncthreads();
    int bin = tid >> 4, i0 = tid & 15;
    const float* src = (bin < 8) ? (maxb + (bin << 8)) : (minb + ((bin - 8) << 8));
    float v = 0.f;
#pragma unroll
    for (int j = 0; j < 16; ++j) v += src[i0 + (j << 4)];
    v += __shfl_xor(v, 1, 64);
    v += __shfl_xor(v, 2, 64);
    v += __shfl_xor(v, 4, 64);
    v += __shfl_xor(v, 8, 64);
    if (i0 == 0) {
        int k = bin & 7;
        int o = ga * 2 + (bin >> 3);
        atomicAdd(&out[(size_t)b * 14336 + (o * NH + h) * NK + k], v);
    }
}

// ---------------- diff precompute: D[b][c][t] = X[t+1]-X[t] ----------------
__global__ void diffK(const float* __restrict__ X, float* __restrict__ D) {
    int t = blockIdx.x * 256 + threadIdx.x;
    int row = blockIdx.y;
    if (t < T0) {
        size_t o = (size_t)row * T0 + t;
        D[o] = (t < T0 - 1) ? (X[o + 1] - X[o]) : 0.f;
    }
}

// ---------------- A body: di 0..5 (d = 1..32), LDS-tiled ----------------
constexpr int TS = 1024;
constexpr int A_TILES = 74;
constexpr int A_BLOCKS_PER_G = 128 * A_TILES;   // 9472
constexpr int A_GROUPS = 12;
constexpr int A_TOTAL_BLOCKS = A_GROUPS * A_BLOCKS_PER_G;  // 113664

template <bool USE_D>
__device__ __forceinline__ void bodyA(int aidx, float* smem,
                                      const float* __restrict__ X,
                                      const float* __restrict__ Dws,
                                      const float* __restrict__ Wt,
                                      const int* __restrict__ idx,
                                      float* __restrict__ out) {
    float* maxb = smem;
    float* Sbuf = smem + 2048;

    const int tid = threadIdx.x;
    const int ga = aidx / A_BLOCKS_PER_G;
    const int rem = aidx - ga * A_BLOCKS_PER_G;
    const int b = rem & 3;                       // XCD locality: b fastest
    const int z = rem >> 2;
    const int h = z & 31;
    const int tile = z >> 5;
    const int di = ga >> 1, diff = ga & 1;
    const int d = 1 << di;
    const int T = T0 - diff;
    const int t0 = tile * TS;
    const int span = TS + 8 * d;

    const int* ip = idx + (ga * NH + h) * 8;
    int offs[8];
#pragma unroll
    for (int i = 0; i < 8; ++i)
        offs[i] = __builtin_amdgcn_readfirstlane((b * NC + ip[i]) * T0);

#pragma unroll
    for (int k = 0; k < 8; ++k) maxb[(k << 8) + tid] = 0.f;

    const float* base = (USE_D && diff) ? Dws : X;
    const bool doDiff = (!USE_D) && diff;
    const int g0 = t0 - 4 * d;                   // even

    if (doDiff) {
        for (int ls = tid; ls < span; ls += 256) {
            int u = g0 + ls;
            float s = 0.f;
            if (u >= 0 && u < T) {
#pragma unroll
                for (int i = 0; i < 8; ++i) s += X[offs[i] + u + 1] - X[offs[i] + u];
            }
            Sbuf[ls] = s;
        }
    } else {
        for (int e = tid * 2; e < span; e += 512) {
            int u = g0 + e;
            F2 s = {0.f, 0.f};
            if (u >= 0 && u + 1 < T) {
#pragma unroll
                for (int i = 0; i < 8; ++i) s += *(const F2*)(base + offs[i] + u);
            } else {
#pragma unroll
                for (int c = 0; c < 2; ++c) {
                    int uc = u + c;
                    float sc = 0.f;
                    if (uc >= 0 && uc < T) {
#pragma unroll
                        for (int i = 0; i < 8; ++i) sc += base[offs[i] + uc];
                    }
                    s[c] = sc;
                }
            }
            *(F2*)(Sbuf + e) = s;
        }
    }
    __syncthreads();

    F2 w2[36];
    load_w2(Wt + (ga * (NK * NH) + h * NK) * 9, w2);

    float bestv[4], worstv[4];
    int validm = 0;
#pragma unroll
    for (int it = 0; it < 4; ++it) {
        const int p = tid + it * 256;
        F2 z2[4];
#pragma unroll
        for (int kp = 0; kp < 4; ++kp) z2[kp] = (F2){0.f, 0.f};
#pragma unroll
        for (int j = 0; j < 9; ++j) {
            float g = Sbuf[p + j * d];
            F2 g2 = {g, g};
#pragma unroll
            for (int kp = 0; kp < 4; ++kp)
                z2[kp] = __builtin_elementwise_fma(w2[j * 4 + kp], g2, z2[kp]);
        }
        float pz[8];
#pragma unroll
        for (int kp = 0; kp < 4; ++kp) {
            pz[2 * kp]     = packK(z2[kp].x, 2 * kp);
            pz[2 * kp + 1] = packK(z2[kp].y, 2 * kp + 1);
        }
        bestv[it]  = max8(pz);
        worstv[it] = min8(pz);
        if (t0 + p < T) validm |= (1 << it);
    }

    unsigned cnt = 0;                            // 8 x 4-bit fields
#pragma unroll
    for (int it = 0; it < 4; ++it) {
        if (validm & (1 << it)) {
            int biK = __float_as_uint(bestv[it]) & 7;
            int wiK = __float_as_uint(worstv[it]) & 7;
            atomicAdd(&maxb[(biK << 8) + tid], bestv[it]);
            cnt += 1u << (wiK << 2);
        }
    }
    __syncthreads();                             // Sbuf reads done; reuse as minstage
#pragma unroll
    for (int k = 0; k < 8; ++k)
        Sbuf[(k << 8) + tid] = (float)((cnt >> (k * 4)) & 15u);

    block_reduce_out(maxb, Sbuf, tid, ga, b, h, out);
}

// ---------------- B body: di 6..13 (d = 64..8192), register chains ----------------
struct BG { int base, m, di, diff; };
constexpr BG BGS[16] = {
    {0,     5,  6, 0}, {640,   5,  6, 1},
    {1280,  5,  7, 0}, {1920,  5,  7, 1},
    {2560,  5,  8, 0}, {3200,  5,  8, 1},
    {3840,  6,  9, 0}, {4608,  6,  9, 1},
    {5376,  8, 10, 0}, {6400,  8, 10, 1},
    {7424,  8, 11, 0}, {8448,  8, 11, 1},
    {9472, 16, 12, 0}, {11520, 16, 12, 1},
    {13568,32, 13, 0}, {17664, 32, 13, 1},
};
constexpr int B_BLOCKS = 21760;

template <bool USE_D>
__device__ __forceinline__ float gatherF(const float* __restrict__ base,
                                         const int* offs, int u, int T, int diffF) {
    float s = 0.f;
    if (u >= 0 && u < T) {
        if (!USE_D && diffF) {
            F2 acc = {0.f, 0.f};
#pragma unroll
            for (int i = 0; i < 8; ++i) {
                F2 t = {base[offs[i] + u], base[offs[i] + u + 1]};
                acc += t;
            }
            s = acc.y - acc.x;
        } else {
            float a0 = base[offs[0] + u], a1 = base[offs[1] + u];
            float a2 = base[offs[2] + u], a3 = base[offs[3] + u];
            float a4 = base[offs[4] + u], a5 = base[offs[5] + u];
            float a6 = base[offs[6] + u], a7 = base[offs[7] + u];
            s = ((a0 + a1) + (a2 + a3)) + ((a4 + a5) + (a6 + a7));
        }
    }
    return s;
}

template <bool USE_D>
__device__ __forceinline__ void bodyB(int bidB, float* smem,
                                      const float* __restrict__ X,
                                      const float* __restrict__ Dws,
                                      const float* __restrict__ Wt,
                                      const int* __restrict__ idx,
                                      float* __restrict__ out) {
    float* accLDS = smem;
    const int tid = threadIdx.x;

    int di = 6, diff = 0, beta = 0;
#pragma unroll
    for (int g = 0; g < 16; ++g) {
        if (bidB >= BGS[g].base && bidB < BGS[g].base + 128 * BGS[g].m) {
            beta = bidB - BGS[g].base;
            di = BGS[g].di; diff = BGS[g].diff;
        }
    }
    const int b = beta & 3;
    const int zz = beta >> 2;
    const int h = zz & 31;
    const int sblk = zz >> 5;

    const int d = 1 << di;
    const int T = T0 - diff;
    const int Q = (T + d - 1) >> di;
    const int ga = di * 2 + diff;
    const int s = sblk * 256 + tid;
    const int q0 = __builtin_amdgcn_readfirstlane((s >> di) * 60);
    const int r = s & (d - 1);

    const int* ip = idx + (ga * NH + h) * 8;
    int offs[8];
#pragma unroll
    for (int i = 0; i < 8; ++i)
        offs[i] = __builtin_amdgcn_readfirstlane((b * NC + ip[i]) * T0);

    F2 w2[36];
    load_w2(Wt + (ga * (NK * NH) + h * NK) * 9, w2);

    const float* base = (USE_D && diff) ? Dws : X;

#pragma unroll
    for (int k = 0; k < 8; ++k) accLDS[(k << 8) + tid] = 0.f;
    float* binsM = accLDS + tid;
    unsigned long long cnt = 0;

    const int t0 = r + q0 * d;
    float buf[10];
    {
        int u = t0 - 4 * d;
#pragma unroll
        for (int m = 0; m < 10; ++m) { buf[m] = gatherF<USE_D>(base, offs, u, T, diff); u += d; }
    }

    for (int outer = 0; outer < 6; ++outer) {
        if (q0 + outer * 10 >= Q) break;
        const int tb = t0 + outer * 10 * d;
#pragma unroll
        for (int ii = 0; ii < 10; ++ii) {
            const int t = tb + ii * d;
            F2 z2[4];
#pragma unroll
            for (int kp = 0; kp < 4; ++kp) z2[kp] = (F2){0.f, 0.f};
#pragma unroll
            for (int j = 0; j < 9; ++j) {
                float g = buf[(ii + j) % 10];
                F2 g2 = {g, g};
#pragma unroll
                for (int kp = 0; kp < 4; ++kp)
                    z2[kp] = __builtin_elementwise_fma(w2[j * 4 + kp], g2, z2[kp]);
            }
            float pz[8];
#pragma unroll
            for (int kp = 0; kp < 4; ++kp) {
                pz[2 * kp]     = packK(z2[kp].x, 2 * kp);
                pz[2 * kp + 1] = packK(z2[kp].y, 2 * kp + 1);
            }
            float best = max8(pz), worst = min8(pz);
            if (t < T) {
                int biK = __float_as_uint(best) & 7;
                int wiK = __float_as_uint(worst) & 7;
                atomicAdd(&binsM[biK << 8], best);
                cnt += 1ull << (wiK << 3);
            }
            buf[ii] = gatherF<USE_D>(base, offs, t + 6 * d, T, diff);
        }
    }

#pragma unroll
    for (int k = 0; k < 8; ++k)
        accLDS[((8 + k) << 8) + tid] = (float)((unsigned)(cnt >> (k * 8)) & 255u);

    block_reduce_out(accLDS, accLDS + 8 * 256, tid, ga, b, h, out);
}

// ---------------- merged kernel: interleave B every 6th block ----------------
// bid = 6k+5, k < B_BLOCKS -> B-block k; else A-block (bid - #B before bid)
constexpr int M_BLOCKS = A_TOTAL_BLOCKS + B_BLOCKS;  // 135424

template <bool USE_D>
__global__ __launch_bounds__(256, 4) void kernM(const float* __restrict__ X,
                                                const float* __restrict__ Dws,
                                                const float* __restrict__ Wt,
                                                const int* __restrict__ idx,
                                                float* __restrict__ out) {
    __shared__ __align__(16) float smem[4096];   // A: maxb|Sbuf ; B: accLDS (16 KB)
    const int bid = blockIdx.x;
    const int g6 = bid / 6;
    const int r6 = bid - g6 * 6;
    if (r6 == 5 && g6 < B_BLOCKS) {
        bodyB<USE_D>(g6, smem, X, Dws, Wt, idx, out);
    } else {
        const int nB = (g6 < B_BLOCKS) ? g6 : B_BLOCKS;
        bodyA<USE_D>(bid - nB, smem, X, Dws, Wt, idx, out);
    }
}

__global__ void zeroK(float* __restrict__ out, int n) {
    int i = blockIdx.x * 256 + threadIdx.x;
    if (i < n) out[i] = 0.f;
}

extern "C" void kernel_launch(void* const* d_in, const int* in_sizes, int n_in,
                              void* d_out, int out_size, void* d_ws, size_t ws_size,
                              hipStream_t stream) {
    const float* X  = (const float*)d_in[0];
    const float* Wt = (const float*)d_in[1];
    const int*  idx = (const int*)d_in[2];
    float* out = (float*)d_out;
    float* Dws = (float*)d_ws;

    const size_t D_BYTES = (size_t)NB * NC * T0 * sizeof(float);   // 20.4 MB
    const bool useD = ws_size >= D_BYTES;

    zeroK<<<(out_size + 255) / 256, 256, 0, stream>>>(out, out_size);
    if (useD) {
        dim3 dg((T0 + 255) / 256, NB * NC);
        diffK<<<dg, 256, 0, stream>>>(X, Dws);
        kernM<true><<<M_BLOCKS, 256, 0, stream>>>(X, Dws, Wt, idx, out);
    } else {
        kernM<false><<<M_BLOCKS, 256, 0, stream>>>(X, Dws, Wt, idx, out);
    }
}

// Round 6
// 1503.089 us; speedup vs baseline: 1.5431x; 1.5431x over previous
//
#include <hip/hip_runtime.h>

typedef float F2 __attribute__((ext_vector_type(2)));

#define NB 4
#define NC 17
#define T0 75000
#define NH 32
#define NK 8

// ---------------- diff precompute: D[b][c][t] = X[t+1]-X[t], D[T0-1]=0 ----------------
__global__ void diffK(const float* __restrict__ X, float* __restrict__ D) {
    int t = blockIdx.x * 256 + threadIdx.x;
    int row = blockIdx.y;
    if (t < T0) {
        size_t o = (size_t)row * T0 + t;
        D[o] = (t < T0 - 1) ? (X[o + 1] - X[o]) : 0.f;
    }
}

// ---------------- kernel A: di 0..5 (d = 1..32), LDS-tiled, R1 body ----------------
// decode: b fastest (XCD locality), then h, tile slowest (cohort shares X window)
constexpr int TS = 1024;
constexpr int A_TILES = 74;
constexpr int A_BLOCKS_PER_G = 128 * A_TILES;   // 9472
constexpr int A_GROUPS = 12;
constexpr int A_TOTAL_BLOCKS = A_GROUPS * A_BLOCKS_PER_G;  // 113664

template <bool USE_D>
__global__ __launch_bounds__(256) void kernA(const float* __restrict__ X,
                                             const float* __restrict__ Dws,
                                             const float* __restrict__ Wt,
                                             const int* __restrict__ idx,
                                             float* __restrict__ out) {
    __shared__ float Sbuf[TS + 8 * 32 + 2];
    __shared__ float red[4][16];

    const int tid = threadIdx.x;
    const int bid = blockIdx.x;
    const int ga = bid / A_BLOCKS_PER_G;
    const int rem = bid - ga * A_BLOCKS_PER_G;
    const int b = rem & 3;
    const int z = rem >> 2;
    const int h = z & 31;
    const int tile = z >> 5;
    const int di = ga >> 1, diff = ga & 1;
    const int d = 1 << di;
    const int T = T0 - diff;
    const int t0 = tile * TS;
    const int span = TS + 8 * d;
    const int g0 = t0 - 4 * d;                   // even

    const int* ip = idx + (ga * NH + h) * 8;
    int offs[8];
#pragma unroll
    for (int i = 0; i < 8; ++i)
        offs[i] = __builtin_amdgcn_readfirstlane((b * NC + ip[i]) * T0);

    if (USE_D) {
        // single staging pass; D rows already padded with 0 at T0-1
        const float* base = diff ? Dws : X;
        for (int e = tid * 2; e < span; e += 512) {
            int u = g0 + e;
            F2 s = {0.f, 0.f};
            if (u >= 0 && u + 1 < T0) {
#pragma unroll
                for (int i = 0; i < 8; ++i) s += *(const F2*)(base + offs[i] + u);
            } else {
#pragma unroll
                for (int c = 0; c < 2; ++c) {
                    int uc = u + c;
                    float sc = 0.f;
                    if (uc >= 0 && uc < T0) {
#pragma unroll
                        for (int i = 0; i < 8; ++i) sc += base[offs[i] + uc];
                    }
                    s[c] = sc;
                }
            }
            if (e + 1 < span) *(F2*)(Sbuf + e) = s;
            else Sbuf[e] = s.x;
        }
    } else {
        // fallback: scalar staging with on-the-fly diff
        for (int ls = tid; ls < span; ls += 256) {
            int u = g0 + ls;
            float s = 0.f;
            if (diff) {
                if (u >= 0 && u < T0 - 1) {
#pragma unroll
                    for (int i = 0; i < 8; ++i) s += X[offs[i] + u + 1] - X[offs[i] + u];
                }
            } else {
                if (u >= 0 && u < T0) {
#pragma unroll
                    for (int i = 0; i < 8; ++i) s += X[offs[i] + u];
                }
            }
            Sbuf[ls] = s;
        }
    }
    __syncthreads();

    const float* wp = Wt + (ga * (NK * NH) + h * NK) * 9;
    float w[72];
#pragma unroll
    for (int i = 0; i < 72; ++i) w[i] = wp[i];   // block-uniform -> SGPRs

    float accM[8], accC[8];
#pragma unroll
    for (int k = 0; k < 8; ++k) { accM[k] = 0.f; accC[k] = 0.f; }

#pragma unroll
    for (int it = 0; it < 4; ++it) {
        int pos = tid + it * 256;
        int t = t0 + pos;
        if (t < T) {
            float zv[8];
#pragma unroll
            for (int k = 0; k < 8; ++k) zv[k] = 0.f;
#pragma unroll
            for (int j = 0; j < 9; ++j) {
                float g = Sbuf[pos + j * d];
#pragma unroll
                for (int k = 0; k < 8; ++k) zv[k] = fmaf(w[k * 9 + j], g, zv[k]);
            }
            float best = zv[0], worst = zv[0];
            int biK = 0, wiK = 0;
#pragma unroll
            for (int k = 1; k < 8; ++k) {
                if (zv[k] > best)  { best = zv[k];  biK = k; }
                if (zv[k] < worst) { worst = zv[k]; wiK = k; }
            }
#pragma unroll
            for (int k = 0; k < 8; ++k) {
                accM[k] += (k == biK) ? best : 0.f;
                accC[k] += (k == wiK) ? 1.f  : 0.f;
            }
        }
    }

    // wave butterfly reduce
#pragma unroll
    for (int k = 0; k < 8; ++k) {
#pragma unroll
        for (int sh = 1; sh < 64; sh <<= 1) {
            accM[k] += __shfl_xor(accM[k], sh, 64);
            accC[k] += __shfl_xor(accC[k], sh, 64);
        }
    }
    int wv = tid >> 6, lane = tid & 63;
    if (lane == 0) {
#pragma unroll
        for (int k = 0; k < 8; ++k) { red[wv][k] = accM[k]; red[wv][8 + k] = accC[k]; }
    }
    __syncthreads();
    if (tid < 16) {
        float v = red[0][tid] + red[1][tid] + red[2][tid] + red[3][tid];
        int which = tid >> 3;
        int k = tid & 7;
        int o = ga * 2 + which;
        atomicAdd(&out[(size_t)b * 14336 + (o * NH + h) * NK + k], v);
    }
}

// ---------------- kernel B: di 6..13 (d = 64..8192), register chains (R4 body) ----------------
struct BG { int base, m, di, diff; };
constexpr BG BGS[16] = {
    {0,     5,  6, 0}, {640,   5,  6, 1},
    {1280,  5,  7, 0}, {1920,  5,  7, 1},
    {2560,  5,  8, 0}, {3200,  5,  8, 1},
    {3840,  6,  9, 0}, {4608,  6,  9, 1},
    {5376,  8, 10, 0}, {6400,  8, 10, 1},
    {7424,  8, 11, 0}, {8448,  8, 11, 1},
    {9472, 16, 12, 0}, {11520, 16, 12, 1},
    {13568,32, 13, 0}, {17664, 32, 13, 1},
};
constexpr int B_BLOCKS = 21760;

__device__ __forceinline__ float packK(float z, int k) {
    unsigned u = (__float_as_uint(z) & 0xFFFFFFF8u) | (unsigned)k;
    return __uint_as_float(u);
}
__device__ __forceinline__ float max8(const float* p) {
    return fmaxf(fmaxf(fmaxf(p[0], p[1]), fmaxf(p[2], p[3])),
                 fmaxf(fmaxf(p[4], p[5]), fmaxf(p[6], p[7])));
}
__device__ __forceinline__ float min8(const float* p) {
    return fminf(fminf(fminf(p[0], p[1]), fminf(p[2], p[3])),
                 fminf(fminf(p[4], p[5]), fminf(p[6], p[7])));
}
__device__ __forceinline__ void load_w2(const float* __restrict__ wp, F2* w2) {
#pragma unroll
    for (int j = 0; j < 9; ++j)
#pragma unroll
        for (int kp = 0; kp < 4; ++kp)
            w2[j * 4 + kp] = (F2){wp[(2 * kp) * 9 + j], wp[(2 * kp + 1) * 9 + j]};
}

template <bool USE_D>
__device__ __forceinline__ float gatherF(const float* __restrict__ base,
                                         const int* offs, int u, int T, int diffF) {
    float s = 0.f;
    if (u >= 0 && u < T) {
        if (!USE_D && diffF) {
            F2 acc = {0.f, 0.f};
#pragma unroll
            for (int i = 0; i < 8; ++i) {
                F2 t = {base[offs[i] + u], base[offs[i] + u + 1]};
                acc += t;
            }
            s = acc.y - acc.x;
        } else {
            float a0 = base[offs[0] + u], a1 = base[offs[1] + u];
            float a2 = base[offs[2] + u], a3 = base[offs[3] + u];
            float a4 = base[offs[4] + u], a5 = base[offs[5] + u];
            float a6 = base[offs[6] + u], a7 = base[offs[7] + u];
            s = ((a0 + a1) + (a2 + a3)) + ((a4 + a5) + (a6 + a7));
        }
    }
    return s;
}

template <bool USE_D>
__global__ __launch_bounds__(256, 8) void kernB(const float* __restrict__ X,
                                                const float* __restrict__ Dws,
                                                const float* __restrict__ Wt,
                                                const int* __restrict__ idx,
                                                float* __restrict__ out) {
    __shared__ float accLDS[16 * 256];
    const int tid = threadIdx.x;
    const int bid = blockIdx.x;

    int di = 6, diff = 0, beta = 0;
#pragma unroll
    for (int g = 0; g < 16; ++g) {
        if (bid >= BGS[g].base && bid < BGS[g].base + 128 * BGS[g].m) {
            beta = bid - BGS[g].base;
            di = BGS[g].di; diff = BGS[g].diff;
        }
    }
    const int b = beta & 3;
    const int zz = beta >> 2;
    const int h = zz & 31;
    const int sblk = zz >> 5;

    const int d = 1 << di;
    const int T = T0 - diff;
    const int Q = (T + d - 1) >> di;
    const int ga = di * 2 + diff;
    const int s = sblk * 256 + tid;
    const int q0 = __builtin_amdgcn_readfirstlane((s >> di) * 60);
    const int r = s & (d - 1);

    const int* ip = idx + (ga * NH + h) * 8;
    int offs[8];
#pragma unroll
    for (int i = 0; i < 8; ++i)
        offs[i] = __builtin_amdgcn_readfirstlane((b * NC + ip[i]) * T0);

    F2 w2[36];
    load_w2(Wt + (ga * (NK * NH) + h * NK) * 9, w2);

    const float* base = (USE_D && diff) ? Dws : X;

#pragma unroll
    for (int k = 0; k < 16; ++k) accLDS[(k << 8) + tid] = 0.f;
    float* binsM = accLDS + tid;
    unsigned long long cnt = 0;

    const int t0 = r + q0 * d;
    float buf[10];
    {
        int u = t0 - 4 * d;
#pragma unroll
        for (int m = 0; m < 10; ++m) { buf[m] = gatherF<USE_D>(base, offs, u, T, diff); u += d; }
    }

    for (int outer = 0; outer < 6; ++outer) {
        if (q0 + outer * 10 >= Q) break;
        const int tb = t0 + outer * 10 * d;
#pragma unroll
        for (int ii = 0; ii < 10; ++ii) {
            const int t = tb + ii * d;
            F2 z2[4];
#pragma unroll
            for (int kp = 0; kp < 4; ++kp) z2[kp] = (F2){0.f, 0.f};
#pragma unroll
            for (int j = 0; j < 9; ++j) {
                float g = buf[(ii + j) % 10];
                F2 g2 = {g, g};
#pragma unroll
                for (int kp = 0; kp < 4; ++kp)
                    z2[kp] = __builtin_elementwise_fma(w2[j * 4 + kp], g2, z2[kp]);
            }
            float pz[8];
#pragma unroll
            for (int kp = 0; kp < 4; ++kp) {
                pz[2 * kp]     = packK(z2[kp].x, 2 * kp);
                pz[2 * kp + 1] = packK(z2[kp].y, 2 * kp + 1);
            }
            float best = max8(pz), worst = min8(pz);
            if (t < T) {
                int biK = __float_as_uint(best) & 7;
                int wiK = __float_as_uint(worst) & 7;
                atomicAdd(&binsM[biK << 8], best);
                cnt += 1ull << (wiK << 3);
            }
            buf[ii] = gatherF<USE_D>(base, offs, t + 6 * d, T, diff);
        }
    }

#pragma unroll
    for (int k = 0; k < 8; ++k)
        accLDS[((8 + k) << 8) + tid] = (float)((unsigned)(cnt >> (k * 8)) & 255u);

    // reduce 16x256 -> 16 atomics
    __syncthreads();
    int bin = tid >> 4, i0 = tid & 15;
    float v = 0.f;
#pragma unroll
    for (int j = 0; j < 16; ++j) v += accLDS[(bin << 8) + i0 + (j << 4)];
    v += __shfl_xor(v, 1, 64);
    v += __shfl_xor(v, 2, 64);
    v += __shfl_xor(v, 4, 64);
    v += __shfl_xor(v, 8, 64);
    if (i0 == 0) {
        int k = bin & 7;
        int o = ga * 2 + (bin >> 3);
        atomicAdd(&out[(size_t)b * 14336 + (o * NH + h) * NK + k], v);
    }
}

__global__ void zeroK(float* __restrict__ out, int n) {
    int i = blockIdx.x * 256 + threadIdx.x;
    if (i < n) out[i] = 0.f;
}

extern "C" void kernel_launch(void* const* d_in, const int* in_sizes, int n_in,
                              void* d_out, int out_size, void* d_ws, size_t ws_size,
                              hipStream_t stream) {
    const float* X  = (const float*)d_in[0];
    const float* Wt = (const float*)d_in[1];
    const int*  idx = (const int*)d_in[2];
    float* out = (float*)d_out;
    float* Dws = (float*)d_ws;

    const size_t D_BYTES = (size_t)NB * NC * T0 * sizeof(float);   // 20.4 MB
    const bool useD = ws_size >= D_BYTES;

    zeroK<<<(out_size + 255) / 256, 256, 0, stream>>>(out, out_size);
    if (useD) {
        dim3 dg((T0 + 255) / 256, NB * NC);
        diffK<<<dg, 256, 0, stream>>>(X, Dws);
        kernA<true><<<A_TOTAL_BLOCKS, 256, 0, stream>>>(X, Dws, Wt, idx, out);
        kernB<true><<<B_BLOCKS, 256, 0, stream>>>(X, Dws, Wt, idx, out);
    } else {
        kernA<false><<<A_TOTAL_BLOCKS, 256, 0, stream>>>(X, Dws, Wt, idx, out);
        kernB<false><<<B_BLOCKS, 256, 0, stream>>>(X, Dws, Wt, idx, out);
    }
}

// Round 7
// 1498.075 us; speedup vs baseline: 1.5482x; 1.0033x over previous
//
#include <hip/hip_runtime.h>

typedef float F2 __attribute__((ext_vector_type(2)));

#define NB 4
#define NC 17
#define T0 75000
#define NH 32
#define NK 8

// ---------------- diff precompute: D[b][c][t] = X[t+1]-X[t], D[T0-1]=0 ----------------
__global__ void diffK(const float* __restrict__ X, float* __restrict__ D) {
    int t = blockIdx.x * 256 + threadIdx.x;
    int row = blockIdx.y;
    if (t < T0) {
        size_t o = (size_t)row * T0 + t;
        D[o] = (t < T0 - 1) ? (X[o + 1] - X[o]) : 0.f;
    }
}

// ---------------- kernel A: di 0..5 (d = 1..32), LDS-tiled, R1 body ----------------
constexpr int TS = 1024;
constexpr int A_TILES = 74;
constexpr int A_BLOCKS_PER_G = 128 * A_TILES;   // 9472
constexpr int A_GROUPS = 12;
constexpr int A_TOTAL_BLOCKS = A_GROUPS * A_BLOCKS_PER_G;  // 113664

template <bool USE_D>
__global__ __launch_bounds__(256) void kernA(const float* __restrict__ X,
                                             const float* __restrict__ Dws,
                                             const float* __restrict__ Wt,
                                             const int* __restrict__ idx,
                                             float* __restrict__ out) {
    __shared__ float Sbuf[TS + 8 * 32 + 2];
    __shared__ float red[4][16];

    const int tid = threadIdx.x;
    const int bid = blockIdx.x;
    const int ga = bid / A_BLOCKS_PER_G;
    const int rem = bid - ga * A_BLOCKS_PER_G;
    const int b = rem & 3;
    const int z = rem >> 2;
    const int h = z & 31;
    const int tile = z >> 5;
    const int di = ga >> 1, diff = ga & 1;
    const int d = 1 << di;
    const int T = T0 - diff;
    const int t0 = tile * TS;
    const int span = TS + 8 * d;
    const int g0 = t0 - 4 * d;                   // even

    const int* ip = idx + (ga * NH + h) * 8;
    int offs[8];
#pragma unroll
    for (int i = 0; i < 8; ++i)
        offs[i] = __builtin_amdgcn_readfirstlane((b * NC + ip[i]) * T0);

    if (USE_D) {
        const float* base = diff ? Dws : X;
        for (int e = tid * 2; e < span; e += 512) {
            int u = g0 + e;
            F2 s = {0.f, 0.f};
            if (u >= 0 && u + 1 < T0) {
#pragma unroll
                for (int i = 0; i < 8; ++i) s += *(const F2*)(base + offs[i] + u);
            } else {
#pragma unroll
                for (int c = 0; c < 2; ++c) {
                    int uc = u + c;
                    float sc = 0.f;
                    if (uc >= 0 && uc < T0) {
#pragma unroll
                        for (int i = 0; i < 8; ++i) sc += base[offs[i] + uc];
                    }
                    s[c] = sc;
                }
            }
            if (e + 1 < span) *(F2*)(Sbuf + e) = s;
            else Sbuf[e] = s.x;
        }
    } else {
        for (int ls = tid; ls < span; ls += 256) {
            int u = g0 + ls;
            float s = 0.f;
            if (diff) {
                if (u >= 0 && u < T0 - 1) {
#pragma unroll
                    for (int i = 0; i < 8; ++i) s += X[offs[i] + u + 1] - X[offs[i] + u];
                }
            } else {
                if (u >= 0 && u < T0) {
#pragma unroll
                    for (int i = 0; i < 8; ++i) s += X[offs[i] + u];
                }
            }
            Sbuf[ls] = s;
        }
    }
    __syncthreads();

    const float* wp = Wt + (ga * (NK * NH) + h * NK) * 9;
    float w[72];
#pragma unroll
    for (int i = 0; i < 72; ++i) w[i] = wp[i];   // block-uniform -> SGPRs

    float accM[8], accC[8];
#pragma unroll
    for (int k = 0; k < 8; ++k) { accM[k] = 0.f; accC[k] = 0.f; }

#pragma unroll
    for (int it = 0; it < 4; ++it) {
        int pos = tid + it * 256;
        int t = t0 + pos;
        if (t < T) {
            float zv[8];
#pragma unroll
            for (int k = 0; k < 8; ++k) zv[k] = 0.f;
#pragma unroll
            for (int j = 0; j < 9; ++j) {
                float g = Sbuf[pos + j * d];
#pragma unroll
                for (int k = 0; k < 8; ++k) zv[k] = fmaf(w[k * 9 + j], g, zv[k]);
            }
            float best = zv[0], worst = zv[0];
            int biK = 0, wiK = 0;
#pragma unroll
            for (int k = 1; k < 8; ++k) {
                if (zv[k] > best)  { best = zv[k];  biK = k; }
                if (zv[k] < worst) { worst = zv[k]; wiK = k; }
            }
#pragma unroll
            for (int k = 0; k < 8; ++k) {
                accM[k] += (k == biK) ? best : 0.f;
                accC[k] += (k == wiK) ? 1.f  : 0.f;
            }
        }
    }

#pragma unroll
    for (int k = 0; k < 8; ++k) {
#pragma unroll
        for (int sh = 1; sh < 64; sh <<= 1) {
            accM[k] += __shfl_xor(accM[k], sh, 64);
            accC[k] += __shfl_xor(accC[k], sh, 64);
        }
    }
    int wv = tid >> 6, lane = tid & 63;
    if (lane == 0) {
#pragma unroll
        for (int k = 0; k < 8; ++k) { red[wv][k] = accM[k]; red[wv][8 + k] = accC[k]; }
    }
    __syncthreads();
    if (tid < 16) {
        float v = red[0][tid] + red[1][tid] + red[2][tid] + red[3][tid];
        int which = tid >> 3;
        int k = tid & 7;
        int o = ga * 2 + which;
        atomicAdd(&out[(size_t)b * 14336 + (o * NH + h) * NK + k], v);
    }
}

// ---------------- kernel B: di 6..13 (d = 64..8192), register chains ----------------
struct BG { int base, m, di, diff; };
constexpr BG BGS[16] = {
    {0,     5,  6, 0}, {640,   5,  6, 1},
    {1280,  5,  7, 0}, {1920,  5,  7, 1},
    {2560,  5,  8, 0}, {3200,  5,  8, 1},
    {3840,  6,  9, 0}, {4608,  6,  9, 1},
    {5376,  8, 10, 0}, {6400,  8, 10, 1},
    {7424,  8, 11, 0}, {8448,  8, 11, 1},
    {9472, 16, 12, 0}, {11520, 16, 12, 1},
    {13568,32, 13, 0}, {17664, 32, 13, 1},
};
constexpr int B_BLOCKS = 21760;

__device__ __forceinline__ float packK(float z, int k) {
    unsigned u = (__float_as_uint(z) & 0xFFFFFFF8u) | (unsigned)k;
    return __uint_as_float(u);
}
__device__ __forceinline__ float max8(const float* p) {
    return fmaxf(fmaxf(fmaxf(p[0], p[1]), fmaxf(p[2], p[3])),
                 fmaxf(fmaxf(p[4], p[5]), fmaxf(p[6], p[7])));
}
__device__ __forceinline__ float min8(const float* p) {
    return fminf(fminf(fminf(p[0], p[1]), fminf(p[2], p[3])),
                 fminf(fminf(p[4], p[5]), fminf(p[6], p[7])));
}
__device__ __forceinline__ void load_w2(const float* __restrict__ wp, F2* w2) {
#pragma unroll
    for (int j = 0; j < 9; ++j)
#pragma unroll
        for (int kp = 0; kp < 4; ++kp)
            w2[j * 4 + kp] = (F2){wp[(2 * kp) * 9 + j], wp[(2 * kp + 1) * 9 + j]};
}

template <bool USE_D>
__device__ __forceinline__ float gatherF(const float* __restrict__ base,
                                         const int* offs, int u, int T, int diffF) {
    float s = 0.f;
    if (u >= 0 && u < T) {
        if (!USE_D && diffF) {
            F2 acc = {0.f, 0.f};
#pragma unroll
            for (int i = 0; i < 8; ++i) {
                F2 t = {base[offs[i] + u], base[offs[i] + u + 1]};
                acc += t;
            }
            s = acc.y - acc.x;
        } else {
            float a0 = base[offs[0] + u], a1 = base[offs[1] + u];
            float a2 = base[offs[2] + u], a3 = base[offs[3] + u];
            float a4 = base[offs[4] + u], a5 = base[offs[5] + u];
            float a6 = base[offs[6] + u], a7 = base[offs[7] + u];
            s = ((a0 + a1) + (a2 + a3)) + ((a4 + a5) + (a6 + a7));
        }
    }
    return s;
}

// (256,4): SGPR budget 200/wave -> w2 stays scalar-resident (the (256,8)
// variant capped SGPRs at ~100, forcing per-iteration weight reloads)
template <bool USE_D>
__global__ __launch_bounds__(256, 4) void kernB(const float* __restrict__ X,
                                                const float* __restrict__ Dws,
                                                const float* __restrict__ Wt,
                                                const int* __restrict__ idx,
                                                float* __restrict__ out) {
    __shared__ float accLDS[16 * 256];
    const int tid = threadIdx.x;
    const int bid = blockIdx.x;

    int di = 6, diff = 0, beta = 0;
#pragma unroll
    for (int g = 0; g < 16; ++g) {
        if (bid >= BGS[g].base && bid < BGS[g].base + 128 * BGS[g].m) {
            beta = bid - BGS[g].base;
            di = BGS[g].di; diff = BGS[g].diff;
        }
    }
    const int b = beta & 3;
    const int zz = beta >> 2;
    const int h = zz & 31;
    const int sblk = zz >> 5;

    const int d = 1 << di;
    const int T = T0 - diff;
    const int Q = (T + d - 1) >> di;
    const int ga = di * 2 + diff;
    const int s = sblk * 256 + tid;
    const int q0 = __builtin_amdgcn_readfirstlane((s >> di) * 60);
    const int r = s & (d - 1);

    const int* ip = idx + (ga * NH + h) * 8;
    int offs[8];
#pragma unroll
    for (int i = 0; i < 8; ++i)
        offs[i] = __builtin_amdgcn_readfirstlane((b * NC + ip[i]) * T0);

    F2 w2[36];
    load_w2(Wt + (ga * (NK * NH) + h * NK) * 9, w2);

    const float* base = (USE_D && diff) ? Dws : X;

#pragma unroll
    for (int k = 0; k < 16; ++k) accLDS[(k << 8) + tid] = 0.f;
    float* binsM = accLDS + tid;
    unsigned long long cnt = 0;

    const int t0 = r + q0 * d;
    float buf[10];
    {
        int u = t0 - 4 * d;
#pragma unroll
        for (int m = 0; m < 10; ++m) { buf[m] = gatherF<USE_D>(base, offs, u, T, diff); u += d; }
    }

    for (int outer = 0; outer < 6; ++outer) {
        if (q0 + outer * 10 >= Q) break;
        const int tb = t0 + outer * 10 * d;
#pragma unroll
        for (int ii = 0; ii < 10; ++ii) {
            const int t = tb + ii * d;
            F2 z2[4];
#pragma unroll
            for (int kp = 0; kp < 4; ++kp) z2[kp] = (F2){0.f, 0.f};
#pragma unroll
            for (int j = 0; j < 9; ++j) {
                float g = buf[(ii + j) % 10];
                F2 g2 = {g, g};
#pragma unroll
                for (int kp = 0; kp < 4; ++kp)
                    z2[kp] = __builtin_elementwise_fma(w2[j * 4 + kp], g2, z2[kp]);
            }
            float pz[8];
#pragma unroll
            for (int kp = 0; kp < 4; ++kp) {
                pz[2 * kp]     = packK(z2[kp].x, 2 * kp);
                pz[2 * kp + 1] = packK(z2[kp].y, 2 * kp + 1);
            }
            float best = max8(pz), worst = min8(pz);
            if (t < T) {
                int biK = __float_as_uint(best) & 7;
                int wiK = __float_as_uint(worst) & 7;
                atomicAdd(&binsM[biK << 8], best);
                cnt += 1ull << (wiK << 3);
            }
            buf[ii] = gatherF<USE_D>(base, offs, t + 6 * d, T, diff);
        }
    }

#pragma unroll
    for (int k = 0; k < 8; ++k)
        accLDS[((8 + k) << 8) + tid] = (float)((unsigned)(cnt >> (k * 8)) & 255u);

    __syncthreads();
    int bin = tid >> 4, i0 = tid & 15;
    float v = 0.f;
#pragma unroll
    for (int j = 0; j < 16; ++j) v += accLDS[(bin << 8) + i0 + (j << 4)];
    v += __shfl_xor(v, 1, 64);
    v += __shfl_xor(v, 2, 64);
    v += __shfl_xor(v, 4, 64);
    v += __shfl_xor(v, 8, 64);
    if (i0 == 0) {
        int k = bin & 7;
        int o = ga * 2 + (bin >> 3);
        atomicAdd(&out[(size_t)b * 14336 + (o * NH + h) * NK + k], v);
    }
}

__global__ void zeroK(float* __restrict__ out, int n) {
    int i = blockIdx.x * 256 + threadIdx.x;
    if (i < n) out[i] = 0.f;
}

extern "C" void kernel_launch(void* const* d_in, const int* in_sizes, int n_in,
                              void* d_out, int out_size, void* d_ws, size_t ws_size,
                              hipStream_t stream) {
    const float* X  = (const float*)d_in[0];
    const float* Wt = (const float*)d_in[1];
    const int*  idx = (const int*)d_in[2];
    float* out = (float*)d_out;
    float* Dws = (float*)d_ws;

    const size_t D_BYTES = (size_t)NB * NC * T0 * sizeof(float);   // 20.4 MB
    const bool useD = ws_size >= D_BYTES;

    zeroK<<<(out_size + 255) / 256, 256, 0, stream>>>(out, out_size);
    if (useD) {
        dim3 dg((T0 + 255) / 256, NB * NC);
        diffK<<<dg, 256, 0, stream>>>(X, Dws);
        kernA<true><<<A_TOTAL_BLOCKS, 256, 0, stream>>>(X, Dws, Wt, idx, out);
        kernB<true><<<B_BLOCKS, 256, 0, stream>>>(X, Dws, Wt, idx, out);
    } else {
        kernA<false><<<A_TOTAL_BLOCKS, 256, 0, stream>>>(X, Dws, Wt, idx, out);
        kernB<false><<<B_BLOCKS, 256, 0, stream>>>(X, Dws, Wt, idx, out);
    }
}